// Round 5
// baseline (3517.487 us; speedup 1.0000x reference)
//
#include <hip/hip_runtime.h>
#include <math.h>

#define N 64
#define LDC 68            // LDS staging leading dim (floats)
#define MAX_SWEEPS 10     // early exit; typical ~6
#define SKIP_TOL2 9e-12f  // skip rotation if gamma^2 <= tol2*a*b (PROVEN at R2; R4's 1e-9 + P-direct failed)

// Raw-hardware approximations (~22-bit): fine for rotation params; final
// eigenvalues recomputed exactly from column norms.
__device__ __forceinline__ float frcp(float x)   { return __builtin_amdgcn_rcpf(x); }
__device__ __forceinline__ float fsqrt_(float x) { return __builtin_amdgcn_sqrtf(x); }
__device__ __forceinline__ float frsq(float x)   { return __builtin_amdgcn_rsqf(x); }
__device__ __forceinline__ float flog_(float x)  { return __builtin_amdgcn_logf(x) * 0.69314718056f; }

// xor-swizzle within 32-lane halves (LDS crossbar, no bank/data traffic)
template <int IMM>
__device__ __forceinline__ float swz(float x) {
    return __int_as_float(__builtin_amdgcn_ds_swizzle(__float_as_int(x), IMM));
}
// DPP full shuffle (quad_perm etc.)
template <int CTRL>
__device__ __forceinline__ float dppmov(float x) {
    return __int_as_float(__builtin_amdgcn_update_dpp(0, __float_as_int(x), CTRL, 0xF, 0xF, true));
}
// gfx950 cross-half swap: new_a = {a.lo, b.lo}, new_b = {a.hi, b.hi}
__device__ __forceinline__ void pl32_swap(float& a, float& b) {
    asm volatile("v_permlane32_swap_b32 %0, %1" : "+v"(a), "+v"(b));
}
// gfx950 row swap: per 32-half: new_a = {a.r0, b.r0}, new_b = {a.r1, b.r1} (16-lane rows)
__device__ __forceinline__ void pl16_swap(float& a, float& b) {
    asm volatile("v_permlane16_swap_b32 %0, %1" : "+v"(a), "+v"(b));
}
__device__ __forceinline__ float bperm(int byteidx, float v) {
    return __int_as_float(__builtin_amdgcn_ds_bpermute(byteidx, __float_as_int(v)));
}
__device__ __forceinline__ float rdlane(float v, int lane) {
    return __int_as_float(__builtin_amdgcn_readlane(__float_as_int(v), lane));
}

__global__ __launch_bounds__(64, 2)
void logeig_kernel(const float* __restrict__ P, float* __restrict__ Out) {
    __shared__ float As[N * LDC];   // staging: load, Cholesky, writeback, epilogue
    __shared__ float lw_s[N];

    const int t = threadIdx.x;      // lane 0..63
    const int bid = blockIdx.x;
    const float* A0 = P + (size_t)bid * (N * N);
    float* O = Out + (size_t)bid * (N * N);

    // ---- Load P (symmetric: col c == row c), coalesced float4. [R3 proven] ----
    {
        const float4* A4 = (const float4*)A0;
        #pragma unroll
        for (int kk = 0; kk < 16; ++kk) {
            int f = kk * 64 + t;
            float4 v = A4[f];
            int e = f << 2;
            int r = e >> 6;
            int i = e & 63;
            *(float4*)&As[r * LDC + i] = v;
        }
    }
    __syncthreads();

    // ---- Cholesky P = L L^T in place, lower triangle, col-major. [R3 proven] ----
    for (int k = 0; k < N; ++k) {
        float dval = fmaxf(As[k * LDC + k], 1e-20f);
        float dinv = frsq(dval);
        {
            int i = k + 1 + t;
            if (i < N) As[k * LDC + i] *= dinv;
        }
        if (t == 0) As[k * LDC + k] = dval * dinv;   // = sqrt(dval)
        __syncthreads();
        for (int j = k + 1 + (t >> 3); j < N; j += 8) {
            float ljk = As[k * LDC + j];
            for (int i = j + (t & 7); i < N; i += 8)
                As[j * LDC + i] = fmaf(-As[k * LDC + i], ljk, As[j * LDC + i]);
        }
        __syncthreads();
    }

    // ---- Zero strict upper triangle (stale P entries). ----
    for (int f = t; f < N * N; f += 64) {
        int cc = f >> 6, i = f & 63;
        if (i < cc) As[cc * LDC + i] = 0.f;
    }
    __syncthreads();

    // ---- Distribute: lane l takes ROW l of L; slot c = column c. ----
    float R[N];
    #pragma unroll
    for (int c2 = 0; c2 < N; ++c2) R[c2] = As[c2 * LDC + t];

    // initial norms: lane l = ||col l||^2 (slot l's norm lives at lane l)
    float nrm;
    {
        float d0 = 0.f, d1 = 0.f, d2 = 0.f, d3 = 0.f;
        const float* cc = &As[t * LDC];
        #pragma unroll
        for (int j = 0; j < 16; ++j) {
            float4 v = *(const float4*)&cc[4 * j];
            d0 = fmaf(v.x, v.x, d0);
            d1 = fmaf(v.y, v.y, d1);
            d2 = fmaf(v.z, v.z, d2);
            d3 = fmaf(v.w, v.w, d3);
        }
        nrm = (d0 + d1) + (d2 + d3);
    }

    // nrm slot-rotation bpermute index (static per lane): new slot s <- old slot pi(s)
    // pi: 0->0, 2->1, even s>=4 -> s-2, odd s<=61 -> s+2, 63->62
    int bidx;
    {
        int pl;
        if (t == 0) pl = 0;
        else if (t == 2) pl = 1;
        else if ((t & 1) == 0) pl = t - 2;
        else if (t == 63) pl = 62;
        else pl = t + 2;
        bidx = pl << 2;
    }

    const bool m8 = (t & 8) != 0, m4 = (t & 4) != 0, m2 = (t & 2) != 0;
    const bool ev = (t & 1) == 0;

    // ---- Brent-Luk systolic one-sided Jacobi. Pairs = fixed slots (2j,2j+1);
    // columns rotate through slots each round (static permutation; sigma^63 = id).
    // Round body is r-invariant: pure VALU + 17 crossbar ops, ZERO barriers.
    #pragma unroll 1
    for (int sweep = 0; sweep < MAX_SWEEPS; ++sweep) {
        int rs = 0;
        #pragma unroll 1
        for (int r = 0; r < 63; ++r) {
            // pair products: lane l contributes row l; value v = pair v
            float Pr[32];
            #pragma unroll
            for (int v = 0; v < 32; ++v) Pr[v] = R[2 * v] * R[2 * v + 1];
            // transposing reduce: after all steps lane l holds gamma of pair (l>>1)
            #pragma unroll
            for (int v = 0; v < 16; ++v) {      // fold lanes ^32, split value bit4=l5
                float a = Pr[v], b = Pr[v + 16];
                pl32_swap(a, b);
                Pr[v] = a + b;
            }
            #pragma unroll
            for (int v = 0; v < 8; ++v) {       // fold lanes ^16, split value bit3=l4
                float a = Pr[v], b = Pr[v + 8];
                pl16_swap(a, b);
                Pr[v] = a + b;
            }
            #pragma unroll
            for (int v = 0; v < 4; ++v) {       // fold ^8, split bit2=l3
                float f0 = Pr[v] + swz<0x201F>(Pr[v]);
                float f1 = Pr[v + 4] + swz<0x201F>(Pr[v + 4]);
                Pr[v] = m8 ? f1 : f0;
            }
            #pragma unroll
            for (int v = 0; v < 2; ++v) {       // fold ^4, split bit1=l2
                float f0 = Pr[v] + swz<0x101F>(Pr[v]);
                float f1 = Pr[v + 2] + swz<0x101F>(Pr[v + 2]);
                Pr[v] = m4 ? f1 : f0;
            }
            {                                    // fold ^2, split bit0=l1
                float f0 = Pr[0] + swz<0x081F>(Pr[0]);
                float f1 = Pr[1] + swz<0x081F>(Pr[1]);
                Pr[0] = m2 ? f1 : f0;
            }
            float gd = Pr[0] + swz<0x041F>(Pr[0]);   // final fold ^1: full 64-lane sum

            // params at lanes 2j,2j+1 (bit-identical on both)
            float other = dppmov<0xB1>(nrm);     // partner slot's norm (xor1)
            float a = ev ? nrm : other;          // ||slot 2j||^2
            float b = ev ? other : nrm;          // ||slot 2j+1||^2
            bool dorot = (gd * gd > SKIP_TOL2 * a * b);
            float tau = (b - a) * 0.5f * frcp(gd);
            float tt = frcp(fabsf(tau) + fsqrt_(fmaf(tau, tau, 1.f)));
            if (tau < 0.f) tt = -tt;
            tt = dorot ? tt : 0.f;
            float c = dorot ? frsq(fmaf(tt, tt, 1.f)) : 1.f;
            float s = dorot ? tt * c : 0.f;
            nrm = fmaf(ev ? -tt : tt, gd, nrm);  // exact norm update (tt=0 if skip)
            rs |= (int)dorot;

            // rotation: coefficients to SGPR, every lane rotates its row elements
            #pragma unroll
            for (int j = 0; j < 32; ++j) {
                float cj = rdlane(c, 2 * j);
                float sj = rdlane(s, 2 * j);
                float t0 = R[2 * j], t1 = R[2 * j + 1];
                R[2 * j]     = cj * t0 - sj * t1;
                R[2 * j + 1] = sj * t0 + cj * t1;
            }

            // slot rotation (ring: X1..X31,Y31..Y0 -> shift by one; X0 fixed)
            {
                float tX31 = R[62], tY0 = R[1];
                #pragma unroll
                for (int j = 31; j >= 2; --j) R[2 * j] = R[2 * j - 2];
                R[2] = tY0;
                #pragma unroll
                for (int j = 0; j <= 30; ++j) R[2 * j + 1] = R[2 * j + 3];
                R[63] = tX31;
                nrm = bperm(bidx, nrm);          // norms follow their columns
            }
        }
        if (!__any(rs)) break;                   // wave-autonomous convergence
    }

    // ---- Writeback columns to LDS (slot layout; permutation-invariant output) ----
    #pragma unroll
    for (int c2 = 0; c2 < N; ++c2) As[c2 * LDC + t] = R[c2];
    __syncthreads();

    // ---- exact eigenvalues: col_k = sigma_k u_k, lambda_k = ||col_k||^2 ----
    {
        float d0 = 0.f, d1 = 0.f, d2 = 0.f, d3 = 0.f;
        const float* cc = &As[t * LDC];
        #pragma unroll
        for (int j = 0; j < 16; ++j) {
            float4 v = *(const float4*)&cc[4 * j];
            d0 = fmaf(v.x, v.x, d0);
            d1 = fmaf(v.y, v.y, d1);
            d2 = fmaf(v.z, v.z, d2);
            d3 = fmaf(v.w, v.w, d3);
        }
        float lam = fmaxf((d0 + d1) + (d2 + d3), 1e-30f);
        lw_s[t] = flog_(lam) * frcp(lam);        // X = sum_k (log l / l) c_k c_k^T
    }
    __syncthreads();

    // ---- X = sum_k lw[k] c_k c_k^T ; lane tile = rows 16ti..+15, cols 4tj..+3 [R3 proven]
    {
        int ti = t >> 4;
        int tj = t & 15;
        float acc[16][4];
        #pragma unroll
        for (int a2 = 0; a2 < 16; ++a2)
            #pragma unroll
            for (int b2 = 0; b2 < 4; ++b2) acc[a2][b2] = 0.f;

        for (int k = 0; k < N; ++k) {
            float w = lw_s[k];
            const float* ck = &As[k * LDC];
            float4 ub = *(const float4*)&ck[4 * tj];
            ub.x *= w; ub.y *= w; ub.z *= w; ub.w *= w;
            float vb[4] = {ub.x, ub.y, ub.z, ub.w};
            float4 ua0 = *(const float4*)&ck[16 * ti + 0];
            float4 ua1 = *(const float4*)&ck[16 * ti + 4];
            float4 ua2 = *(const float4*)&ck[16 * ti + 8];
            float4 ua3 = *(const float4*)&ck[16 * ti + 12];
            float va[16] = {ua0.x, ua0.y, ua0.z, ua0.w,
                            ua1.x, ua1.y, ua1.z, ua1.w,
                            ua2.x, ua2.y, ua2.z, ua2.w,
                            ua3.x, ua3.y, ua3.z, ua3.w};
            #pragma unroll
            for (int a2 = 0; a2 < 16; ++a2)
                #pragma unroll
                for (int b2 = 0; b2 < 4; ++b2)
                    acc[a2][b2] = fmaf(va[a2], vb[b2], acc[a2][b2]);
        }
        #pragma unroll
        for (int a2 = 0; a2 < 16; ++a2) {
            float4 vout = make_float4(acc[a2][0], acc[a2][1], acc[a2][2], acc[a2][3]);
            ((float4*)O)[(16 * ti + a2) * 16 + tj] = vout;
        }
    }
}

extern "C" void kernel_launch(void* const* d_in, const int* in_sizes, int n_in,
                              void* d_out, int out_size, void* d_ws, size_t ws_size,
                              hipStream_t stream) {
    const float* P = (const float*)d_in[0];
    float* Out = (float*)d_out;
    int nmat = in_sizes[0] / (N * N);    // 8192
    logeig_kernel<<<dim3(nmat), dim3(64), 0, stream>>>(P, Out);
}